// Round 3
// baseline (224.316 us; speedup 1.0000x reference)
//
#include <hip/hip_runtime.h>
#include <hip/hip_bf16.h>

// ---------- types ----------
typedef __attribute__((ext_vector_type(8))) short bf16x8;   // 8 bf16 in 4 VGPRs
typedef __attribute__((ext_vector_type(4))) float f32x4;    // MFMA accumulator
typedef __attribute__((ext_vector_type(8))) unsigned short u16x8;
typedef __attribute__((ext_vector_type(4), aligned(4))) float f32x4u;  // dword-aligned vec load

static __device__ __forceinline__ unsigned short f2bf(float f) {
    // fp32 -> bf16 round-to-nearest-even (inputs are finite)
    union { float f; unsigned int u; } v; v.f = f;
    unsigned int u = v.u;
    u += 0x7FFFu + ((u >> 16) & 1u);
    return (unsigned short)(u >> 16);
}

// ---------- K1: fused convert + transpose + GEMM ----------
// V[b][m][n] = sum_k W[m][k] * x_vit[b][k][n] + bias[m]
// M=256, N=1024 (=32x32 pixels), K=512. Reads W and x_vit fp32 directly,
// converts to bf16 while staging into LDS (B transposed in-LDS). 64x64 tile
// per block, 4 waves 2x2, each wave 2x2 of 16x16x32 bf16 MFMAs.
// LDS tiles padded to stride 40 shorts (80 B = 5*16 B): keeps ds_read_b128
// 16 B-aligned while breaking the stride-32 8-way bank-group conflict.
#define TS 40
__global__ void __launch_bounds__(256) gemm_fused(const float* __restrict__ W,
                                                  const float* __restrict__ Xv,
                                                  const float* __restrict__ bias,
                                                  float* __restrict__ V) {
    __shared__ __align__(16) unsigned short As[64 * TS];  // [m][k]
    __shared__ __align__(16) unsigned short Bs[64 * TS];  // [n][k]

    int b  = blockIdx.z;
    int m0 = blockIdx.y * 64;
    int n0 = blockIdx.x * 64;
    int t  = threadIdx.x;
    int wave = t >> 6;
    int lane = t & 63;
    int wm = (wave >> 1) * 32;
    int wn = (wave & 1) * 32;
    int l15  = lane & 15;
    int quad = lane >> 4;

    // A staging: thread t covers W row m0+(t>>2), k-chunk (t&3)*8 .. +7
    const float* Ag = W + (size_t)(m0 + (t >> 2)) * 512 + ((t & 3) << 3);
    unsigned short* Asw = As + (t >> 2) * TS + ((t & 3) << 3);
    // B staging: thread t covers x_vit k-row (t>>3), n-chunk n0+(t&7)*8 .. +7
    const float* Bg = Xv + ((size_t)b * 512 + (t >> 3)) * 1024 + n0 + ((t & 7) << 3);
    int bs_n = (t & 7) << 3;
    int bs_k = t >> 3;

    f32x4 acc[2][2] = {};

    for (int k0 = 0; k0 < 512; k0 += 32) {
        float4 av0 = *(const float4*)(Ag + k0);
        float4 av1 = *(const float4*)(Ag + k0 + 4);
        float4 bv0 = *(const float4*)(Bg + (size_t)k0 * 1024);
        float4 bv1 = *(const float4*)(Bg + (size_t)k0 * 1024 + 4);

        u16x8 aw;
        aw[0] = f2bf(av0.x); aw[1] = f2bf(av0.y); aw[2] = f2bf(av0.z); aw[3] = f2bf(av0.w);
        aw[4] = f2bf(av1.x); aw[5] = f2bf(av1.y); aw[6] = f2bf(av1.z); aw[7] = f2bf(av1.w);
        *(u16x8*)Asw = aw;

        unsigned short bw[8];
        bw[0] = f2bf(bv0.x); bw[1] = f2bf(bv0.y); bw[2] = f2bf(bv0.z); bw[3] = f2bf(bv0.w);
        bw[4] = f2bf(bv1.x); bw[5] = f2bf(bv1.y); bw[6] = f2bf(bv1.z); bw[7] = f2bf(bv1.w);
        #pragma unroll
        for (int j = 0; j < 8; ++j)
            Bs[(bs_n + j) * TS + bs_k] = bw[j];   // in-LDS transpose: [n][k]

        __syncthreads();

        // A[m=l15][k=quad*8+j], B[k=quad*8+j][n=l15] -- k-contiguous b128 reads
        bf16x8 a0 = *(const bf16x8*)(As + (wm + l15) * TS + quad * 8);
        bf16x8 a1 = *(const bf16x8*)(As + (wm + 16 + l15) * TS + quad * 8);
        bf16x8 b0 = *(const bf16x8*)(Bs + (wn + l15) * TS + quad * 8);
        bf16x8 b1 = *(const bf16x8*)(Bs + (wn + 16 + l15) * TS + quad * 8);

        acc[0][0] = __builtin_amdgcn_mfma_f32_16x16x32_bf16(a0, b0, acc[0][0], 0, 0, 0);
        acc[0][1] = __builtin_amdgcn_mfma_f32_16x16x32_bf16(a0, b1, acc[0][1], 0, 0, 0);
        acc[1][0] = __builtin_amdgcn_mfma_f32_16x16x32_bf16(a1, b0, acc[1][0], 0, 0, 0);
        acc[1][1] = __builtin_amdgcn_mfma_f32_16x16x32_bf16(a1, b1, acc[1][1], 0, 0, 0);
        __syncthreads();
    }

    // D mapping (verified): col = lane&15, row = quad*4 + reg
    #pragma unroll
    for (int mi = 0; mi < 2; ++mi)
        #pragma unroll
        for (int ni = 0; ni < 2; ++ni)
            #pragma unroll
            for (int r = 0; r < 4; ++r) {
                int gm = m0 + wm + mi * 16 + quad * 4 + r;
                int gn = n0 + wn + ni * 16 + l15;
                V[((size_t)b * 256 + gm) * 1024 + gn] = acc[mi][ni][r] + bias[gm];
            }
}

// ---------- K2: fused bilinear-upsample + per-pixel cosine ----------
// 1 block per (b, output row h). 256 threads = 32 w-quads x 8 channel-slices.
// Each thread: 4 consecutive w-pixels (float4 x-loads), 32 channels.
// V corners: 2 float4 loads/channel (top & bottom source rows, cols cb..cb+3),
// row-blended once, then per-pixel precomputed column weights (edge clamp folded).
__global__ void __launch_bounds__(256) fused_cos(const float* __restrict__ xcnn, // [8][256][128][128]
                                                 const float* __restrict__ V,    // [8][256][32][32]
                                                 float* __restrict__ out) {      // [8][1][128][128]
    __shared__ float red[8 * 385];   // [cs][ (q*4+px)*3 + j ], stride 385 breaks conflicts

    int bh = blockIdx.x;
    int b  = bh >> 7;
    int h  = bh & 127;
    int t  = threadIdx.x;
    int q  = t & 31;     // w-quad: pixels 4q..4q+3
    int cs = t >> 5;     // channel slice: channels cs*32..cs*32+31

    // ----- row interpolation (same for all 4 pixels of this thread) -----
    float sy = (h + 0.5f) * 0.25f - 0.5f;
    float fy = floorf(sy);
    float dy = sy - fy;
    int y0 = max(0, min(31, (int)fy));
    int y1 = max(0, min(31, (int)fy + 1));

    // ----- column weights per pixel, folded with edge clamp -----
    int cb = max(0, min(28, q - 1));      // float4 base col, covers all needed cols
    float a[4][4];
    #pragma unroll
    for (int px = 0; px < 4; ++px) {
        #pragma unroll
        for (int j = 0; j < 4; ++j) a[px][j] = 0.f;
        int w = q * 4 + px;
        float sx = (w + 0.5f) * 0.25f - 0.5f;
        float fx = floorf(sx);
        float dx = sx - fx;
        int x0 = max(0, min(31, (int)fx));
        int x1 = max(0, min(31, (int)fx + 1));
        a[px][x0 - cb] += 1.f - dx;
        a[px][x1 - cb] += dx;
    }

    const float* xp = xcnn + ((size_t)(b * 256 + cs * 32) * 16384) + h * 128 + q * 4;
    const float* vt = V + ((size_t)(b * 256 + cs * 32) * 1024) + y0 * 32 + cb;
    const float* vb = V + ((size_t)(b * 256 + cs * 32) * 1024) + y1 * 32 + cb;
    float ry = dy, ry0 = 1.f - dy;

    float dot[4] = {0.f, 0.f, 0.f, 0.f};
    float nx [4] = {0.f, 0.f, 0.f, 0.f};
    float nv [4] = {0.f, 0.f, 0.f, 0.f};

    #pragma unroll 8
    for (int c = 0; c < 32; ++c) {
        float4  xv  = *(const float4*)(xp + (size_t)c * 16384);
        f32x4u  top = *(const f32x4u*)(vt + (size_t)c * 1024);
        f32x4u  bot = *(const f32x4u*)(vb + (size_t)c * 1024);
        float bl0 = ry0 * top[0] + ry * bot[0];
        float bl1 = ry0 * top[1] + ry * bot[1];
        float bl2 = ry0 * top[2] + ry * bot[2];
        float bl3 = ry0 * top[3] + ry * bot[3];
        float xs[4] = {xv.x, xv.y, xv.z, xv.w};
        #pragma unroll
        for (int px = 0; px < 4; ++px) {
            float v = a[px][0] * bl0 + a[px][1] * bl1 + a[px][2] * bl2 + a[px][3] * bl3;
            dot[px] += xs[px] * v;
            nx [px] += xs[px] * xs[px];
            nv [px] += v * v;
        }
    }

    // ----- cross-slice reduction in LDS -----
    float* my = red + cs * 385;
    #pragma unroll
    for (int px = 0; px < 4; ++px) {
        int o = (q * 4 + px) * 3;
        my[o + 0] = dot[px];
        my[o + 1] = nx[px];
        my[o + 2] = nv[px];
    }
    __syncthreads();

    if (t < 128) {                 // one thread per output pixel of this row
        int px = t & 3;
        int q2 = t >> 2;
        int o  = (q2 * 4 + px) * 3;
        float d = 0.f, sx2 = 0.f, sv2 = 0.f;
        #pragma unroll
        for (int s = 0; s < 8; ++s) {
            d   += red[s * 385 + o + 0];
            sx2 += red[s * 385 + o + 1];
            sv2 += red[s * 385 + o + 2];
        }
        out[(size_t)b * 16384 + h * 128 + q2 * 4 + px] =
            d / (sqrtf(sx2) * sqrtf(sv2) + 1e-8f);
    }
}

extern "C" void kernel_launch(void* const* d_in, const int* in_sizes, int n_in,
                              void* d_out, int out_size, void* d_ws, size_t ws_size,
                              hipStream_t stream) {
    const float* x_cnn = (const float*)d_in[0];  // [8][256][128][128]
    const float* x_vit = (const float*)d_in[1];  // [8][512][32][32]
    const float* W     = (const float*)d_in[2];  // [256][512]
    const float* bias  = (const float*)d_in[3];  // [256]
    float* out = (float*)d_out;                  // [8][1][128][128] fp32

    float* V = (float*)d_ws;                     // 8*256*1024 f32 = 8 MB scratch

    gemm_fused<<<dim3(16, 4, 8), 256, 0, stream>>>(W, x_vit, bias, V);
    fused_cos<<<1024, 256, 0, stream>>>(x_cnn, V, out);
}